// Round 7
// baseline (305.451 us; speedup 1.0000x reference)
//
#include <hip/hip_runtime.h>
#include <hip/hip_cooperative_groups.h>
#include <stdint.h>

namespace cg = cooperative_groups;

// DBSCAN-on-voxel-grid, exact port of the JAX reference for batch_size==1.
// Grid 512x512, eps=1.5 => 8-connected adjacency, min_samples=5 (voxels,
// incl. self), clusters with <20 voxels dropped.
// R7: single cooperative kernel (256 blocks x 256 threads, grid.sync between
// phases) replaces R6's 7-dispatch pipeline; merge/attach process 4 cells per
// thread sharing one word's loaded context.

#define GRIDW 512
#define WPR 16        // bitmap words per row
#define NWORDS 8192   // 512*512/32
#define NB 256
#define NT 256
#define TOT (NB * NT) // 65536 threads
#define NONE 0xFFFFFFFFu

// ---- ws layout (uint32 units) ----
#define OFF_OCC    0       // 8192: occupancy bitmap
#define OFF_CNT    8192    // 8192: per-root voxel counts
#define OFF_ROOTBM 16384   // 256
#define OFF_KEEPBM 16640   // 256
#define ZERO_WORDS 16896   // zeroed in P0
#define OFF_BSUM   16896   // 256: per-block scan totals
#define OFF_RPRE   17152   // 256: exclusive root-rank prefix per rootbm word
#define OFF_CM     17408   // 8192: core mask per word
#define OFF_LAB    25600   // 8192: union-find / final labels (by rank)
#define OFF_PRE    33792   // 8192: exclusive voxel-rank prefix per word

// per-position horizontal (west+self+east) 2-bit counts for a row of 32 cells
__device__ __forceinline__ void hsum(uint32_t l, uint32_t c, uint32_t r,
                                     uint32_t& h0, uint32_t& h1) {
  uint32_t Wb = (c << 1) | (l >> 31);
  uint32_t Eb = (c >> 1) | (r << 31);
  h0 = Wb ^ c ^ Eb;
  h1 = (Wb & c) | (Eb & (Wb ^ c));
}

// per-position (sum of three 2-bit row counts) >= 5 (bit-sliced adders)
__device__ __forceinline__ uint32_t ge5(uint32_t a0, uint32_t a1, uint32_t b0,
                                        uint32_t b1, uint32_t c0, uint32_t c1) {
  uint32_t u0 = a0 ^ b0, cy = a0 & b0;
  uint32_t t = a1 ^ b1;
  uint32_t u1 = t ^ cy;
  uint32_t u2 = (a1 & b1) | (cy & t);
  uint32_t v0 = u0 ^ c0, k0 = u0 & c0;
  uint32_t t2 = u1 ^ c1;
  uint32_t v1 = t2 ^ k0;
  uint32_t k1 = (u1 & c1) | (k0 & t2);
  uint32_t v2 = u2 ^ k1;
  uint32_t v3 = u2 & k1;
  return v3 | (v2 & (v1 | v0));  // count in {5..9}
}

__device__ __forceinline__ uint32_t aread(uint32_t* p) {
  return __hip_atomic_load(p, __ATOMIC_RELAXED, __HIP_MEMORY_SCOPE_AGENT);
}

// find root with guarded path compression: links only ever DECREASE
// (monotone invariant => no cycles, guaranteed termination).
__device__ __forceinline__ uint32_t findc(uint32_t* L, uint32_t x) {
  uint32_t r = x, p = aread(&L[r]);
  while (p != r) { r = p; p = aread(&L[r]); }
  while (x > r) {
    uint32_t nx = aread(&L[x]);
    if (nx <= r) break;
    atomicCAS(&L[x], nx, r);  // best effort, only writes a smaller value
    x = nx;
  }
  return r;
}

// link larger root under smaller => final root == min core rank of component
__device__ __forceinline__ void unite(uint32_t* L, uint32_t a, uint32_t b) {
  for (;;) {
    a = findc(L, a);
    b = findc(L, b);
    if (a == b) return;
    uint32_t lo = min(a, b), hi = max(a, b);
    if (atomicCAS(&L[hi], hi, lo) == hi) return;
    a = lo; b = hi;
  }
}

__global__ __launch_bounds__(NT) void cluster_ck(const float* __restrict__ pts,
                                                 float* __restrict__ out,
                                                 uint32_t* __restrict__ ws,
                                                 int npts) {
  cg::grid_group grid = cg::this_grid();
  const int tid = threadIdx.x;
  const int gid = blockIdx.x * NT + tid;
  const int lane = tid & 63, wv = tid >> 6;
  __shared__ uint32_t wsum[4];
  __shared__ int smax;

  uint32_t* occ = ws + OFF_OCC;
  uint32_t* cm = ws + OFF_CM;
  uint32_t* lab = ws + OFF_LAB;
  uint32_t* pre = ws + OFF_PRE;
  uint32_t* cnt = ws + OFF_CNT;
  uint32_t* bsum = ws + OFF_BSUM;

  // ---- P0: zero state, init union-find ----
  if (gid < ZERO_WORDS) ws[gid] = 0u;
  if (gid < NWORDS) lab[gid] = (uint32_t)gid;
  grid.sync();

  // ---- P1: voxelize (identical f32 ops to jnp) ----
  int myCell = -1;
  if (gid < npts) {
    float x = pts[gid * 5 + 1];
    float y = pts[gid * 5 + 2];
    int cx = (int)floorf((x - (-51.2f)) / 0.2f);
    int cy = (int)floorf((y - (-51.2f)) / 0.2f);
    cx = min(max(cx, 0), GRIDW - 1);
    cy = min(max(cy, 0), GRIDW - 1);
    myCell = cy * GRIDW + cx;
    atomicOr(&occ[myCell >> 5], 1u << (myCell & 31));
  }
  grid.sync();

  // ---- P2a: per-word popcount + core mask; block-level scan ----
  uint32_t s = 0;
  if (gid < NWORDS) {
    uint32_t cB = occ[gid];
    s = __popc(cB);
    int y = gid >> 4, wx = gid & 15;
    uint32_t lB = wx ? occ[gid - 1] : 0u;
    uint32_t rB = (wx < 15) ? occ[gid + 1] : 0u;
    uint32_t cA = 0, lA = 0, rA = 0, cC = 0, lC = 0, rC = 0;
    if (y > 0) { int wa = gid - WPR; cA = occ[wa]; lA = wx ? occ[wa - 1] : 0u; rA = (wx < 15) ? occ[wa + 1] : 0u; }
    if (y < GRIDW - 1) { int wc = gid + WPR; cC = occ[wc]; lC = wx ? occ[wc - 1] : 0u; rC = (wx < 15) ? occ[wc + 1] : 0u; }
    uint32_t a0, a1, b0, b1, c0, c1;
    hsum(lA, cA, rA, a0, a1); hsum(lB, cB, rB, b0, b1); hsum(lC, cC, rC, c0, c1);
    cm[gid] = ge5(a0, a1, b0, b1, c0, c1) & cB;
  }
  uint32_t inc = s;
  for (int d = 1; d < 64; d <<= 1) { uint32_t t = __shfl_up(inc, d); if (lane >= d) inc += t; }
  if (lane == 63) wsum[wv] = inc;
  __syncthreads();
  uint32_t woff = 0;
  for (int k = 0; k < wv; k++) woff += wsum[k];
  uint32_t binc = woff + inc;  // inclusive within block
  if (tid == NT - 1) bsum[blockIdx.x] = binc;
  grid.sync();

  // ---- P2b: block 0 scans the 32 nonzero block totals ----
  if (blockIdx.x == 0 && tid < 32) {
    uint32_t u = bsum[tid];
    for (int d = 1; d < 32; d <<= 1) { uint32_t t = __shfl_up(u, d); if (tid >= d) u += t; }
    bsum[tid] = u;  // inclusive
  }
  grid.sync();

  // ---- P2c: write exclusive voxel-rank prefix per word ----
  if (gid < NWORDS) {
    uint32_t off = blockIdx.x ? bsum[blockIdx.x - 1] : 0u;
    pre[gid] = off + binc - s;
  }
  grid.sync();

  // ---- P3: merge core-core edges (E, S, SE, SW), 4 cells/thread ----
  {
    int wi = gid >> 3;
    uint32_t cw = cm[wi];
    uint32_t nib = (cw >> ((gid & 7) << 2)) & 0xFu;
    if (nib) {
      int wx = wi & 15, y = wi >> 4;
      uint32_t cB = occ[wi];
      int rbase = pre[wi];
      bool hasS = y < GRIDW - 1;
      uint32_t cmS = hasS ? cm[wi + WPR] : 0u;
      uint32_t occS = hasS ? occ[wi + WPR] : 0u;
      int rS = hasS ? (int)pre[wi + WPR] : 0;
      for (int j = 0; j < 4; j++) {
        int b = ((gid & 7) << 2) + j;
        if (!((cw >> b) & 1)) continue;
        int r = rbase + __popc(cB & ((1u << b) - 1u));
        bool eC = (b < 31) ? ((cw >> (b + 1)) & 1) : ((wx < 15) ? (cm[wi + 1] & 1) : false);
        if (eC) unite(lab, r, (b < 31) ? r + 1 : pre[wi + 1]);
        if (hasS) {
          if ((cmS >> b) & 1) unite(lab, r, rS + __popc(occS & ((1u << b) - 1u)));
          bool seC = (b < 31) ? ((cmS >> (b + 1)) & 1) : ((wx < 15) ? (cm[wi + WPR + 1] & 1) : false);
          if (seC) unite(lab, r, (b < 31) ? rS + __popc(occS & ((2u << b) - 1u)) : pre[wi + WPR + 1]);
          bool swC = (b > 0) ? ((cmS >> (b - 1)) & 1) : ((wx > 0) ? (cm[wi + WPR - 1] >> 31) : false);
          if (swC) unite(lab, r, (b > 0) ? rS + __popc(occS & ((1u << (b - 1)) - 1u)) : rS - 1);
        }
      }
    }
  }
  grid.sync();

  // ---- P4: compress cores + border attach + voxel counts, 4 cells/thread ----
  {
    int wi = gid >> 3;
    uint32_t cB = occ[wi];
    uint32_t nib = (cB >> ((gid & 7) << 2)) & 0xFu;
    if (nib) {
      int wx = wi & 15, y = wi >> 4;
      uint32_t cw = cm[wi];
      int rbase = pre[wi];
      bool hasN = y > 0, hasS = y < GRIDW - 1;
      uint32_t cmN = 0, occN = 0, cmS = 0, occS = 0;
      int rN = 0, rS = 0;
      if (hasN) { cmN = cm[wi - WPR]; occN = occ[wi - WPR]; rN = pre[wi - WPR]; }
      if (hasS) { cmS = cm[wi + WPR]; occS = occ[wi + WPR]; rS = pre[wi + WPR]; }
      for (int j = 0; j < 4; j++) {
        int b = ((gid & 7) << 2) + j;
        if (!((cB >> b) & 1)) continue;
        int r = rbase + __popc(cB & ((1u << b) - 1u));
        if ((cw >> b) & 1) {
          uint32_t root = findc(lab, r);
          lab[r] = root;
          if (root == (uint32_t)r) atomicOr(&ws[OFF_ROOTBM + (r >> 5)], 1u << (r & 31));
          atomicAdd(&cnt[root], 1u);
        } else {
          uint32_t m = NONE;
          bool wC = (b > 0) ? ((cw >> (b - 1)) & 1) : ((wx > 0) ? (cm[wi - 1] >> 31) : false);
          if (wC) m = min(m, findc(lab, (b > 0) ? r - 1 : rbase - 1));
          bool eC = (b < 31) ? ((cw >> (b + 1)) & 1) : ((wx < 15) ? (cm[wi + 1] & 1) : false);
          if (eC) m = min(m, findc(lab, (b < 31) ? r + 1 : pre[wi + 1]));
          if (hasN) {
            if ((cmN >> b) & 1) m = min(m, findc(lab, rN + __popc(occN & ((1u << b) - 1u))));
            bool neC = (b < 31) ? ((cmN >> (b + 1)) & 1) : ((wx < 15) ? (cm[wi - WPR + 1] & 1) : false);
            if (neC) m = min(m, findc(lab, (b < 31) ? rN + __popc(occN & ((2u << b) - 1u)) : pre[wi - WPR + 1]));
            bool nwC = (b > 0) ? ((cmN >> (b - 1)) & 1) : ((wx > 0) ? (cm[wi - WPR - 1] >> 31) : false);
            if (nwC) m = min(m, findc(lab, (b > 0) ? rN + __popc(occN & ((1u << (b - 1)) - 1u)) : rN - 1));
          }
          if (hasS) {
            if ((cmS >> b) & 1) m = min(m, findc(lab, rS + __popc(occS & ((1u << b) - 1u))));
            bool seC = (b < 31) ? ((cmS >> (b + 1)) & 1) : ((wx < 15) ? (cm[wi + WPR + 1] & 1) : false);
            if (seC) m = min(m, findc(lab, (b < 31) ? rS + __popc(occS & ((2u << b) - 1u)) : pre[wi + WPR + 1]));
            bool swC = (b > 0) ? ((cmS >> (b - 1)) & 1) : ((wx > 0) ? (cm[wi + WPR - 1] >> 31) : false);
            if (swC) m = min(m, findc(lab, (b > 0) ? rS + __popc(occS & ((1u << (b - 1)) - 1u)) : rS - 1));
          }
          lab[r] = m;  // NONE => noise; non-core ranks are never UF parents
          if (m != NONE) atomicAdd(&cnt[m], 1u);
        }
      }
    }
  }
  grid.sync();

  // ---- P5: block 0 — dense root numbering, keep filter, max kept id ----
  if (blockIdx.x == 0) {
    if (tid == 0) smax = -1;
    __syncthreads();
    uint32_t rb = ws[OFF_ROOTBM + tid];
    uint32_t v = __popc(rb);
    uint32_t rinc = v;
    for (int d = 1; d < 64; d <<= 1) { uint32_t t = __shfl_up(rinc, d); if (lane >= d) rinc += t; }
    if (lane == 63) wsum[wv] = rinc;
    __syncthreads();
    uint32_t roff = 0;
    for (int k = 0; k < wv; k++) roff += wsum[k];
    uint32_t excl = roff + rinc - v;
    ws[OFF_RPRE + tid] = excl;
    uint32_t keep = 0;
    int mx = -1, d = (int)excl;
    while (rb) {
      int b = __ffs(rb) - 1; rb &= rb - 1;
      int r = tid * 32 + b;
      if (cnt[r] >= 20u) { keep |= 1u << b; mx = d; }
      d++;
    }
    ws[OFF_KEEPBM + tid] = keep;
    if (mx >= 0) atomicMax(&smax, mx);
    __syncthreads();
    if (tid == 0) out[npts] = (float)(smax + 1);
  }
  grid.sync();

  // ---- P6: scatter dense labels back to points ----
  if (gid < npts) {
    int wi = myCell >> 5;
    int r = pre[wi] + __popc(occ[wi] & ((1u << (myCell & 31)) - 1u));
    uint32_t l = lab[r];
    float o = -1.0f;
    if (l != NONE && ((ws[OFF_KEEPBM + (l >> 5)] >> (l & 31)) & 1)) {
      int dnum = ws[OFF_RPRE + (l >> 5)] +
                 __popc(ws[OFF_ROOTBM + (l >> 5)] & ((1u << (l & 31)) - 1u));
      o = (float)dnum;
    }
    out[gid] = o;
  }
}

extern "C" void kernel_launch(void* const* d_in, const int* in_sizes, int n_in,
                              void* d_out, int out_size, void* d_ws, size_t ws_size,
                              hipStream_t stream) {
  const float* pts = (const float*)d_in[0];
  int npts = in_sizes[0] / 5;  // points are (N,5) float32
  uint32_t* ws = (uint32_t*)d_ws;
  float* out = (float*)d_out;
  void* args[] = {(void*)&pts, (void*)&out, (void*)&ws, (void*)&npts};
  hipLaunchCooperativeKernel((void*)cluster_ck, dim3(NB), dim3(NT), args, 0,
                             stream);
}

// Round 8
// 113.700 us; speedup vs baseline: 2.6865x; 2.6865x over previous
//
#include <hip/hip_runtime.h>
#include <stdint.h>

// DBSCAN-on-voxel-grid, exact port of the JAX reference for batch_size==1.
// Grid 512x512, eps=1.5 => 8-connected adjacency, min_samples=5 (voxels,
// incl. self), clusters with <20 voxels dropped.
// R8: union-find on CELL IDS (rank is monotone in cell id, so min-rank root
// == min-cell-id root and dense numbering is preserved) -> the whole rank
// prefix-scan phase and all rank popcs are deleted. Core masks recomputed
// on the fly (SWAR, R3-proven helpers). 6 dispatches, no memset, no coop
// grid.sync (R7 showed cross-XCD sync costs ~30us each).

#define GRIDW 512
#define WPR 16        // bitmap words per row
#define NWORDS 8192   // 512*512/32
#define NCELLS 262144
#define NONE 0xFFFFFFFFu

// ---- ws layout (uint32 units) ----
#define OFF_OCC    0       // 8192  (zeroed in k_init)
#define OFF_ROOTBM 8192    // 8192  (zeroed in k_init; indexed by cell)
#define OFF_KEEPBM 16384   // 8192  (fully written in k_finish)
#define OFF_RPRE   24576   // 8192  (fully written in k_finish)
#define OFF_LAB    32768   // 262144: union-find / final labels (by cell id)
#define OFF_CNT    294912  // 262144: per-root voxel counts (zeroed in k_init)

// per-position horizontal (west+self+east) 2-bit counts for a row of 32 cells
__device__ __forceinline__ void hsum(uint32_t l, uint32_t c, uint32_t r,
                                     uint32_t& h0, uint32_t& h1) {
  uint32_t Wb = (c << 1) | (l >> 31);
  uint32_t Eb = (c >> 1) | (r << 31);
  h0 = Wb ^ c ^ Eb;
  h1 = (Wb & c) | (Eb & (Wb ^ c));
}

// per-position (sum of three 2-bit row counts) >= 5 (bit-sliced adders)
__device__ __forceinline__ uint32_t ge5(uint32_t a0, uint32_t a1, uint32_t b0,
                                        uint32_t b1, uint32_t c0, uint32_t c1) {
  uint32_t u0 = a0 ^ b0, cy = a0 & b0;
  uint32_t t = a1 ^ b1;
  uint32_t u1 = t ^ cy;
  uint32_t u2 = (a1 & b1) | (cy & t);
  uint32_t v0 = u0 ^ c0, k0 = u0 & c0;
  uint32_t t2 = u1 ^ c1;
  uint32_t v1 = t2 ^ k0;
  uint32_t k1 = (u1 & c1) | (k0 & t2);
  uint32_t v2 = u2 ^ k1;
  uint32_t v3 = u2 & k1;
  return v3 | (v2 & (v1 | v0));  // count in {5..9}
}

// core status of bit0 of the word RIGHT of rows (up,center,down): args are
// (centerUp,rightUp, centerMid,rightMid, centerDn,rightDn)
__device__ __forceinline__ uint32_t coreRbit(uint32_t cU, uint32_t rU, uint32_t cM,
                                             uint32_t rM, uint32_t cD, uint32_t rD) {
  if (!(rM & 1u)) return 0u;
  int n = __popc((cU >> 31) | ((rU & 3u) << 1)) +
          __popc((cM >> 31) | ((rM & 3u) << 1)) +
          __popc((cD >> 31) | ((rD & 3u) << 1));
  return n >= 5 ? 1u : 0u;
}

// core status of bit31 of the word LEFT of rows
__device__ __forceinline__ uint32_t coreLbit(uint32_t cU, uint32_t lU, uint32_t cM,
                                             uint32_t lM, uint32_t cD, uint32_t lD) {
  if (!(lM >> 31)) return 0u;
  int n = __popc(((lU >> 30) & 3u) | ((cU & 1u) << 2)) +
          __popc(((lM >> 30) & 3u) | ((cM & 1u) << 2)) +
          __popc(((lD >> 30) & 3u) | ((cD & 1u) << 2));
  return n >= 5 ? 1u : 0u;
}

__device__ __forceinline__ uint32_t aread(uint32_t* p) {
  return __hip_atomic_load(p, __ATOMIC_RELAXED, __HIP_MEMORY_SCOPE_AGENT);
}

// find root with guarded path compression: links only ever DECREASE
// (monotone invariant => no cycles, guaranteed termination).
__device__ __forceinline__ uint32_t findc(uint32_t* L, uint32_t x) {
  uint32_t r = x, p = aread(&L[r]);
  while (p != r) { r = p; p = aread(&L[r]); }
  while (x > r) {
    uint32_t nx = aread(&L[x]);
    if (nx <= r) break;
    atomicCAS(&L[x], nx, r);  // best effort, only writes a smaller value
    x = nx;
  }
  return r;
}

// link larger root under smaller => final root == min core CELL of component
__device__ __forceinline__ void unite(uint32_t* L, uint32_t a, uint32_t b) {
  for (;;) {
    a = findc(L, a);
    b = findc(L, b);
    if (a == b) return;
    uint32_t lo = min(a, b), hi = max(a, b);
    if (atomicCAS(&L[hi], hi, lo) == hi) return;
    a = lo; b = hi;
  }
}

// K1: zero occ/rootbm/cnt, identity-init lab
__global__ void k_init(uint32_t* __restrict__ ws) {
  int i = blockIdx.x * 256 + threadIdx.x;
  ws[OFF_LAB + i] = (uint32_t)i;
  ws[OFF_CNT + i] = 0u;
  if (i < NWORDS) { ws[OFF_OCC + i] = 0u; ws[OFF_ROOTBM + i] = 0u; }
}

// K2: voxelize points -> occupancy bits (identical f32 ops to jnp)
__global__ void k_vox(const float* __restrict__ pts, uint32_t* __restrict__ ws,
                      int npts) {
  int i = blockIdx.x * 256 + threadIdx.x;
  if (i >= npts) return;
  float x = pts[i * 5 + 1];
  float y = pts[i * 5 + 2];
  int cx = (int)floorf((x - (-51.2f)) / 0.2f);
  int cy = (int)floorf((y - (-51.2f)) / 0.2f);
  cx = min(max(cx, 0), GRIDW - 1);
  cy = min(max(cy, 0), GRIDW - 1);
  int cell = cy * GRIDW + cx;
  atomicOr(&ws[OFF_OCC + (cell >> 5)], 1u << (cell & 31));
}

// K3: per-cell union of core-core edges (E, S, SE, SW), core masks on the fly
__global__ void k_merge(uint32_t* __restrict__ ws) {
  int cell = blockIdx.x * 256 + threadIdx.x;
  const uint32_t* occ = ws + OFF_OCC;
  uint32_t* lab = ws + OFF_LAB;
  int wi = cell >> 5, b = cell & 31, wx = wi & 15, y = cell >> 9;
  uint32_t cB = occ[wi];
  if (!((cB >> b) & 1)) return;
  uint32_t lB = wx ? occ[wi - 1] : 0u;
  uint32_t rB = (wx < 15) ? occ[wi + 1] : 0u;
  uint32_t cA = 0, lA = 0, rA = 0, cC = 0, lC = 0, rC = 0, cD = 0, lD = 0, rD = 0;
  if (y > 0) { int w = wi - WPR; cA = occ[w]; lA = wx ? occ[w - 1] : 0u; rA = (wx < 15) ? occ[w + 1] : 0u; }
  if (y < GRIDW - 1) { int w = wi + WPR; cC = occ[w]; lC = wx ? occ[w - 1] : 0u; rC = (wx < 15) ? occ[w + 1] : 0u; }
  if (y < GRIDW - 2) { int w = wi + 2 * WPR; cD = occ[w]; lD = wx ? occ[w - 1] : 0u; rD = (wx < 15) ? occ[w + 1] : 0u; }
  uint32_t hA0, hA1, hB0, hB1, hC0, hC1, hD0, hD1;
  hsum(lA, cA, rA, hA0, hA1); hsum(lB, cB, rB, hB0, hB1);
  hsum(lC, cC, rC, hC0, hC1); hsum(lD, cD, rD, hD0, hD1);
  uint32_t cmB = ge5(hA0, hA1, hB0, hB1, hC0, hC1) & cB;
  if (!((cmB >> b) & 1)) return;  // not core
  bool eC = (b < 31) ? (((cmB >> (b + 1)) & 1) != 0)
                     : (coreRbit(cA, rA, cB, rB, cC, rC) != 0);
  if (eC) unite(lab, cell, cell + 1);
  if (y < GRIDW - 1) {
    uint32_t cmS = ge5(hB0, hB1, hC0, hC1, hD0, hD1) & cC;
    if ((cmS >> b) & 1) unite(lab, cell, cell + GRIDW);
    bool seC = (b < 31) ? (((cmS >> (b + 1)) & 1) != 0)
                        : (coreRbit(cB, rB, cC, rC, cD, rD) != 0);
    if (seC) unite(lab, cell, cell + GRIDW + 1);
    bool swC = (b > 0) ? (((cmS >> (b - 1)) & 1) != 0)
                       : (coreLbit(cB, lB, cC, lC, cD, lD) != 0);
    if (swC) unite(lab, cell, cell + GRIDW - 1);
  }
}

// K4: per-cell compress (core) or border attach (non-core) + voxel counts
__global__ void k_cb(uint32_t* __restrict__ ws) {
  int cell = blockIdx.x * 256 + threadIdx.x;
  const uint32_t* occ = ws + OFF_OCC;
  uint32_t* lab = ws + OFF_LAB;
  uint32_t* cnt = ws + OFF_CNT;
  int wi = cell >> 5, b = cell & 31, wx = wi & 15, y = cell >> 9;
  uint32_t cB = occ[wi];
  if (!((cB >> b) & 1)) return;
  uint32_t lB = wx ? occ[wi - 1] : 0u;
  uint32_t rB = (wx < 15) ? occ[wi + 1] : 0u;
  uint32_t cZ = 0, lZ = 0, rZ = 0, cA = 0, lA = 0, rA = 0;
  uint32_t cC = 0, lC = 0, rC = 0, cD = 0, lD = 0, rD = 0;
  if (y > 1) { int w = wi - 2 * WPR; cZ = occ[w]; lZ = wx ? occ[w - 1] : 0u; rZ = (wx < 15) ? occ[w + 1] : 0u; }
  if (y > 0) { int w = wi - WPR; cA = occ[w]; lA = wx ? occ[w - 1] : 0u; rA = (wx < 15) ? occ[w + 1] : 0u; }
  if (y < GRIDW - 1) { int w = wi + WPR; cC = occ[w]; lC = wx ? occ[w - 1] : 0u; rC = (wx < 15) ? occ[w + 1] : 0u; }
  if (y < GRIDW - 2) { int w = wi + 2 * WPR; cD = occ[w]; lD = wx ? occ[w - 1] : 0u; rD = (wx < 15) ? occ[w + 1] : 0u; }
  uint32_t hZ0, hZ1, hA0, hA1, hB0, hB1, hC0, hC1, hD0, hD1;
  hsum(lZ, cZ, rZ, hZ0, hZ1); hsum(lA, cA, rA, hA0, hA1); hsum(lB, cB, rB, hB0, hB1);
  hsum(lC, cC, rC, hC0, hC1); hsum(lD, cD, rD, hD0, hD1);
  uint32_t cw0 = ge5(hA0, hA1, hB0, hB1, hC0, hC1) & cB;
  if ((cw0 >> b) & 1) {
    uint32_t root = findc(lab, cell);
    lab[cell] = root;
    if (root == (uint32_t)cell) atomicOr(&ws[OFF_ROOTBM + wi], 1u << b);
    atomicAdd(&cnt[root], 1u);
  } else {
    uint32_t cwm1 = ge5(hZ0, hZ1, hA0, hA1, hB0, hB1) & cA;
    uint32_t cw1 = ge5(hB0, hB1, hC0, hC1, hD0, hD1) & cC;
    uint32_t m = NONE;
    bool t;
    t = (b > 0) ? (((cw0 >> (b - 1)) & 1) != 0) : (coreLbit(cA, lA, cB, lB, cC, lC) != 0);
    if (t) m = min(m, findc(lab, cell - 1));
    t = (b < 31) ? (((cw0 >> (b + 1)) & 1) != 0) : (coreRbit(cA, rA, cB, rB, cC, rC) != 0);
    if (t) m = min(m, findc(lab, cell + 1));
    if (y > 0) {
      if ((cwm1 >> b) & 1) m = min(m, findc(lab, cell - GRIDW));
      t = (b > 0) ? (((cwm1 >> (b - 1)) & 1) != 0) : (coreLbit(cZ, lZ, cA, lA, cB, lB) != 0);
      if (t) m = min(m, findc(lab, cell - GRIDW - 1));
      t = (b < 31) ? (((cwm1 >> (b + 1)) & 1) != 0) : (coreRbit(cZ, rZ, cA, rA, cB, rB) != 0);
      if (t) m = min(m, findc(lab, cell - GRIDW + 1));
    }
    if (y < GRIDW - 1) {
      if ((cw1 >> b) & 1) m = min(m, findc(lab, cell + GRIDW));
      t = (b > 0) ? (((cw1 >> (b - 1)) & 1) != 0) : (coreLbit(cB, lB, cC, lC, cD, lD) != 0);
      if (t) m = min(m, findc(lab, cell + GRIDW - 1));
      t = (b < 31) ? (((cw1 >> (b + 1)) & 1) != 0) : (coreRbit(cB, rB, cC, rC, cD, rD) != 0);
      if (t) m = min(m, findc(lab, cell + GRIDW + 1));
    }
    lab[cell] = m;  // NONE => noise; non-core cells are never UF parents
    if (m != NONE) atomicAdd(&cnt[m], 1u);
  }
}

// K5: dense root numbering (prefix over rootbm), keep filter, max kept id
__global__ void k_finish(uint32_t* __restrict__ ws, float* __restrict__ out,
                         int npts) {
  __shared__ uint32_t wsum[4];
  __shared__ int smax;
  int tid = threadIdx.x;
  if (tid == 0) smax = -1;
  int base = tid * 32;
  uint32_t s = 0;
  for (int j = 0; j < 32; j++) s += __popc(ws[OFF_ROOTBM + base + j]);
  int lane = tid & 63, wv = tid >> 6;
  uint32_t inc = s;
  for (int d = 1; d < 64; d <<= 1) { uint32_t t = __shfl_up(inc, d); if (lane >= d) inc += t; }
  if (lane == 63) wsum[wv] = inc;
  __syncthreads();
  uint32_t woff = 0;
  for (int k = 0; k < wv; k++) woff += wsum[k];
  uint32_t excl = woff + inc - s;
  int mx = -1;
  for (int j = 0; j < 32; j++) {
    uint32_t rbw = ws[OFF_ROOTBM + base + j];
    ws[OFF_RPRE + base + j] = excl;
    uint32_t rb = rbw, keep = 0;
    int d = (int)excl;
    while (rb) {
      int b2 = __ffs(rb) - 1; rb &= rb - 1;
      int r = (base + j) * 32 + b2;
      if (ws[OFF_CNT + r] >= 20u) { keep |= 1u << b2; mx = d; }
      d++;
    }
    ws[OFF_KEEPBM + base + j] = keep;
    excl += __popc(rbw);
  }
  if (mx >= 0) atomicMax(&smax, mx);
  __syncthreads();
  if (tid == 0) out[npts] = (float)(smax + 1);
}

// K6: scatter dense labels back to points
__global__ void k_scatter(const float* __restrict__ pts,
                          const uint32_t* __restrict__ ws,
                          float* __restrict__ out, int npts) {
  int i = blockIdx.x * 256 + threadIdx.x;
  if (i >= npts) return;
  float x = pts[i * 5 + 1];
  float y = pts[i * 5 + 2];
  int cx = (int)floorf((x - (-51.2f)) / 0.2f);  // identical math to k_vox
  int cy = (int)floorf((y - (-51.2f)) / 0.2f);
  cx = min(max(cx, 0), GRIDW - 1);
  cy = min(max(cy, 0), GRIDW - 1);
  int cell = cy * GRIDW + cx;
  uint32_t l = ws[OFF_LAB + cell];
  float o = -1.0f;
  if (l != NONE) {
    if ((ws[OFF_KEEPBM + (l >> 5)] >> (l & 31)) & 1) {
      int dnum = ws[OFF_RPRE + (l >> 5)] +
                 __popc(ws[OFF_ROOTBM + (l >> 5)] & ((1u << (l & 31)) - 1u));
      o = (float)dnum;
    }
  }
  out[i] = o;
}

extern "C" void kernel_launch(void* const* d_in, const int* in_sizes, int n_in,
                              void* d_out, int out_size, void* d_ws, size_t ws_size,
                              hipStream_t stream) {
  const float* pts = (const float*)d_in[0];
  int npts = in_sizes[0] / 5;  // points are (N,5) float32
  uint32_t* ws = (uint32_t*)d_ws;
  float* out = (float*)d_out;
  int pblocks = (npts + 255) / 256;
  k_init<<<NCELLS / 256, 256, 0, stream>>>(ws);
  k_vox<<<pblocks, 256, 0, stream>>>(pts, ws, npts);
  k_merge<<<NCELLS / 256, 256, 0, stream>>>(ws);
  k_cb<<<NCELLS / 256, 256, 0, stream>>>(ws);
  k_finish<<<1, 256, 0, stream>>>(ws, out, npts);
  k_scatter<<<pblocks, 256, 0, stream>>>(pts, ws, out, npts);
}